// Round 2
// baseline (292.683 us; speedup 1.0000x reference)
//
#include <hip/hip_runtime.h>

// CRF forward loss, MI355X — exp-domain formulation.
// 256 blocks x 64 threads: block = (batch, chain); chain 0 = partition,
// chain 1 = tag_partition. Each chain is one wave, no barriers.
// State u_i = 2^(st_i - Mg); step: u'_j = sum_i E_ij * u_i, E = 2^(sc*log2e).
// E is state-independent -> computed in the prefetch shadow, off the chain.

constexpr int SEQ = 256;
constexpr int NTAG = 48;
constexpr int START_TAG = 46;
constexpr int END_TAG = 47;
constexpr float L2E = 1.4426950408889634f; // log2(e)
constexpr float LN2 = 0.6931471805599453f;

__device__ __forceinline__ float fexp2(float x) { return __builtin_amdgcn_exp2f(x); }
__device__ __forceinline__ float flog2(float x) { return __builtin_amdgcn_logf(x); }

__global__ __launch_bounds__(64, 1)
void crf_chain_kernel(const float* __restrict__ S,
                      const void* __restrict__ tgtv,
                      const void* __restrict__ mskv,
                      float* __restrict__ ws)
{
    const int bid  = blockIdx.x;
    const int b    = bid & 127;           // batch
    const int tagc = bid >> 7;            // 0 = partition, 1 = tag_partition
    const int j    = threadIdx.x;         // lane = output tag column
    const bool jok = (j < NTAG);
    const int jj   = jok ? j : 0;         // clamped column for address safety

    // --- dtype detection: packed bool (1B) vs int32 (mask[0..3] all true) ---
    const bool pack8 = (((const int*)mskv)[0] != 1);
    const unsigned char* msk8  = (const unsigned char*)mskv;
    const int*           msk32 = (const int*)mskv;
    const unsigned char* tgt8  = (const unsigned char*)tgtv;
    const int*           tgt32 = (const int*)tgtv;

    // --- sequence length via ballots (mask row = 256 entries, 4 per lane) ---
    int len = 0;
    #pragma unroll
    for (int r = 0; r < 4; ++r) {
        int idx = b * SEQ + r * 64 + j;
        int mm = pack8 ? (msk8[idx] != 0) : (msk32[idx] != 0);
        len += (int)__popcll(__ballot(mm));
    }

    __shared__ __align__(16) float su[64];   // u broadcast buffer (48 used)

    const size_t sb = (size_t)b * SEQ * NTAG * NTAG;
    const float bias = jok ? 0.0f : -200.0f; // pad lanes: exp2(x-200) == 0

    // --- t = 0 init: st0_j = sc[0,START,j]*L2E (log2 domain) ---
    float st0 = S[sb + START_TAG * NTAG + jj] * L2E;
    if (!jok) st0 = -1e30f;
    float M0 = st0;
    #pragma unroll
    for (int off = 1; off < 64; off <<= 1) M0 = fmaxf(M0, __shfl_xor(M0, off));
    float u = jok ? fexp2(st0 - M0) : 0.0f;
    if (tagc && jok) {
        int ti = b * SEQ * NTAG + j;
        int tv = pack8 ? (int)tgt8[ti] : tgt32[ti];
        if (tv) u = 0.0f;
    }
    float Mg = M0;
    su[j] = u;                                // in-order LDS, single wave

    // --- depth-2 prefetch: raw scores for t=1 (A) and t=2 (B); len >= 128 ---
    const float* Sp = S + sb + jj;
    float rawA[48], rawB[48], E[48];
    #pragma unroll
    for (int i = 0; i < 48; ++i) rawA[i] = Sp[(size_t)1 * 2304 + i * 48];
    #pragma unroll
    for (int i = 0; i < 48; ++i) rawB[i] = Sp[(size_t)2 * 2304 + i * 48];
    #pragma unroll
    for (int i = 0; i < 48; ++i) E[i] = fexp2(fmaf(rawA[i], L2E, bias)); // E(t=1)

    const float4* suv = (const float4*)su;

    // body(rfill, rmid, t): issue loads for t+2 into rfill; dot with E (step t);
    // build E(t+1) from rmid. All register indices compile-time (full unroll).
    auto body = [&](float (&rfill)[48], float (&rmid)[48], int t) {
        if (t + 2 < len) {
            #pragma unroll
            for (int i = 0; i < 48; ++i)
                rfill[i] = Sp[(size_t)(t + 2) * 2304 + i * 48];
        }
        int tv = 0;
        if (tagc) {
            int ti = (b * SEQ + t) * NTAG + jj;
            tv = pack8 ? (int)tgt8[ti] : tgt32[ti];
        }
        // dot: u'_j = sum_i E[i] * u_i   (u broadcast from LDS, conflict-free)
        float a0 = 0.f, a1 = 0.f, a2 = 0.f, a3 = 0.f;
        #pragma unroll
        for (int i = 0; i < 12; ++i) {
            float4 q = suv[i];
            a0 = fmaf(E[4 * i + 0], q.x, a0);
            a1 = fmaf(E[4 * i + 1], q.y, a1);
            a2 = fmaf(E[4 * i + 2], q.z, a2);
            a3 = fmaf(E[4 * i + 3], q.w, a3);
        }
        float un = (a0 + a1) + (a2 + a3);
        if (tagc && tv) un = 0.0f;            // target mask: exact zero
        // periodic renorm (uniform branch): keep max(u) in [0.5, 1)
        if ((t & 7) == 0) {
            float mx = un;
            #pragma unroll
            for (int off = 1; off < 64; off <<= 1) mx = fmaxf(mx, __shfl_xor(mx, off));
            int ex = (int)((__float_as_uint(mx) >> 23) & 0xFF) - 126; // frexp exp
            un = ldexpf(un, -ex);
            Mg += (float)ex;
        }
        su[j] = un;                           // program-order after reads: safe
        u = un;
        if (t + 1 < len) {                    // build E for next step (off-chain)
            #pragma unroll
            for (int i = 0; i < 48; ++i)
                E[i] = fexp2(fmaf(rmid[i], L2E, bias));
        }
    };

    int t = 1;
    for (; t + 1 < len; t += 2) {
        body(rawA, rawB, t);
        body(rawB, rawA, t + 1);
    }
    if (t < len) body(rawA, rawB, t);

    if (j == END_TAG) {
        float r = (Mg + flog2(u)) * LN2;      // back to ln domain
        if (tagc) r = (u == 0.0f) ? 0.0f : -r; // tp==NINF -> contribute 0; else minus
        ws[bid] = r;
    }
}

__global__ void crf_reduce_kernel(const float* __restrict__ ws, float* __restrict__ out)
{
    int l = threadIdx.x;                      // 64 threads
    float v = (ws[l] + ws[l + 64]) + (ws[l + 128] + ws[l + 192]);
    #pragma unroll
    for (int off = 32; off > 0; off >>= 1) v += __shfl_down(v, off);
    if (l == 0) out[0] = v;
}

extern "C" void kernel_launch(void* const* d_in, const int* in_sizes, int n_in,
                              void* d_out, int out_size, void* d_ws, size_t ws_size,
                              hipStream_t stream)
{
    const float* S   = (const float*)d_in[0];
    const void*  tgt = d_in[1];
    const void*  msk = d_in[2];
    float* out = (float*)d_out;
    float* ws  = (float*)d_ws;

    crf_chain_kernel<<<256, 64, 0, stream>>>(S, tgt, msk, ws);
    crf_reduce_kernel<<<1, 64, 0, stream>>>(ws, out);
}

// Round 3
// 209.865 us; speedup vs baseline: 1.3946x; 1.3946x over previous
//
#include <hip/hip_runtime.h>

// CRF forward loss, MI355X — exp-domain, 8-wave split, 1 raw-barrier/step.
// Grid 256 = (batch 128) x (chain 2). Block 512 = 8 waves.
// State u_i = 2^(st_i - Mg) replicated in all waves (lane = tag j).
// Step: partial^w_j = sum_{c} E[i0+c][j] * u_{i0+c};  u'_j = sum_w partial^w_j.
// E = 2^(sc*log2e) is state-independent -> built off-chain from reg prefetch.

constexpr int SEQ = 256;
constexpr int NTAG = 48;
constexpr int START_TAG = 46;
constexpr int END_TAG = 47;
constexpr float L2E = 1.4426950408889634f; // log2(e)
constexpr float LN2 = 0.6931471805599453f;
constexpr int W = 8;   // waves
constexpr int C = 6;   // i-rows per wave

__device__ __forceinline__ float fexp2(float x) { return __builtin_amdgcn_exp2f(x); }
__device__ __forceinline__ float flog2(float x) { return __builtin_amdgcn_logf(x); }
__device__ __forceinline__ float rlane(float v, int lane) {
    return __uint_as_float(__builtin_amdgcn_readlane(__float_as_uint(v), lane));
}

__global__ __launch_bounds__(512, 1)
void crf_chain_kernel(const float* __restrict__ S,
                      const void* __restrict__ tgtv,
                      const void* __restrict__ mskv,
                      float* __restrict__ ws)
{
    const int bid  = blockIdx.x;
    const int b    = bid & 127;          // batch
    const int tagc = bid >> 7;           // 0: partition, 1: tag_partition
    const int tid  = threadIdx.x;
    const int k    = tid >> 6;           // wave id
    const int j    = tid & 63;           // lane = output tag column
    const bool jok = (j < NTAG);
    const int jj   = jok ? j : 0;
    const int i0   = k * C;

    // --- dtype detection: packed bool (1B) vs int32 (mask[0..3] all true) ---
    const bool pack8 = (((const int*)mskv)[0] != 1);
    const unsigned char* msk8  = (const unsigned char*)mskv;
    const int*           msk32 = (const int*)mskv;
    const unsigned char* tgt8  = (const unsigned char*)tgtv;
    const int*           tgt32 = (const int*)tgtv;

    // --- sequence length via ballots (256 mask entries, 4 per lane) ---
    int len = 0;
    #pragma unroll
    for (int r = 0; r < 4; ++r) {
        int idx = b * SEQ + r * 64 + j;
        int mm = pack8 ? (msk8[idx] != 0) : (msk32[idx] != 0);
        len += (int)__popcll(__ballot(mm));
    }

    __shared__ float s_part[2][W][64];   // double-buffered partials

    const size_t sb   = (size_t)b * SEQ * NTAG * NTAG;
    const float  bias = jok ? 0.0f : -200.0f;  // pad columns -> E ~ 0
    const float* Sp   = S + sb + (size_t)i0 * NTAG + jj;  // + t*2304 + c*48

    // --- t=0 init: st0_j = sc[0,START,j]*log2e; u = 2^(st0 - M0) ---
    float st0 = S[sb + START_TAG * NTAG + jj] * L2E;
    if (!jok) st0 = -1e30f;
    float M0 = st0;
    #pragma unroll
    for (int off = 1; off < 64; off <<= 1) M0 = fmaxf(M0, __shfl_xor(M0, off));
    float u = jok ? fexp2(st0 - M0) : 0.0f;
    if (tagc && jok) {
        int ti = b * SEQ * NTAG + j;
        int tv0 = pack8 ? (int)tgt8[ti] : tgt32[ti];
        if (tv0) u = 0.0f;
    }
    float Mg = M0;

    // --- depth-2 register prefetch: raw(t=1)->rA, raw(t=2)->rB, E(t=1)->EA ---
    float rA[C], rB[C], EA[C], EB[C];
    #pragma unroll
    for (int c = 0; c < C; ++c) rA[c] = Sp[(size_t)1 * 2304 + c * NTAG];
    #pragma unroll
    for (int c = 0; c < C; ++c) rB[c] = Sp[(size_t)2 * 2304 + c * NTAG];
    #pragma unroll
    for (int c = 0; c < C; ++c) EA[c] = fexp2(fmaf(rA[c], L2E, bias));

    // step t: consume Ecur; fill rFill <- scores(t+2); build Eoth <- exp2(rOth).
    auto step = [&](float (&Ecur)[C], float (&Eoth)[C],
                    float (&rOth)[C], float (&rFill)[C], int t) {
        if (t + 2 < len) {
            #pragma unroll
            for (int c = 0; c < C; ++c)
                rFill[c] = Sp[(size_t)(t + 2) * 2304 + c * NTAG];
        }
        __builtin_amdgcn_sched_barrier(0);   // pin prefetch issue here
        int tv = 0;
        if (tagc) {
            int ti = (b * SEQ + t) * NTAG + jj;
            tv = pack8 ? (int)tgt8[ti] : tgt32[ti];
        }
        // this wave's partial: sum_c E[c]*u_{i0+c} (u broadcast via readlane)
        float p0 = 0.f, p1 = 0.f;
        #pragma unroll
        for (int c = 0; c < C; c += 2) {
            p0 = fmaf(Ecur[c],     rlane(u, i0 + c),     p0);
            p1 = fmaf(Ecur[c + 1], rlane(u, i0 + c + 1), p1);
        }
        s_part[t & 1][k][j] = p0 + p1;
        // build next step's E (state-independent, off the serial chain)
        if (t + 1 < len) {
            #pragma unroll
            for (int c = 0; c < C; ++c)
                Eoth[c] = fexp2(fmaf(rOth[c], L2E, bias));
        }
        // raw barrier: order LDS, do NOT drain vmcnt (keep prefetch in flight)
        asm volatile("s_waitcnt lgkmcnt(0)\n\ts_barrier" ::: "memory");
        float q0 = s_part[t & 1][0][j] + s_part[t & 1][1][j];
        float q1 = s_part[t & 1][2][j] + s_part[t & 1][3][j];
        float q2 = s_part[t & 1][4][j] + s_part[t & 1][5][j];
        float q3 = s_part[t & 1][6][j] + s_part[t & 1][7][j];
        float un = (q0 + q1) + (q2 + q3);
        if (tagc && tv) un = 0.0f;           // target mask: exact zero
        if (!jok) un = 0.0f;                 // pad columns
        if ((t & 7) == 0) {                  // renorm: keep max(u) in [0.5,1)
            float mx = un;
            #pragma unroll
            for (int off = 1; off < 64; off <<= 1) mx = fmaxf(mx, __shfl_xor(mx, off));
            int ex = (int)((__float_as_uint(mx) >> 23) & 0xFF) - 126;
            un = ldexpf(un, -ex);
            Mg += (float)ex;
        }
        u = un;
    };

    int t = 1;
    for (; t + 1 < len; t += 2) {
        step(EA, EB, rB, rA, t);
        step(EB, EA, rA, rB, t + 1);
    }
    if (t < len) step(EA, EB, rB, rA, t);

    if (k == 0 && j == END_TAG) {
        float r = (Mg + flog2(u)) * LN2;     // back to ln domain
        if (tagc) r = (u == 0.0f) ? 0.0f : -r;
        ws[bid] = r;
    }
}

__global__ void crf_reduce_kernel(const float* __restrict__ ws, float* __restrict__ out)
{
    int l = threadIdx.x;                     // 64 threads
    float v = (ws[l] + ws[l + 64]) + (ws[l + 128] + ws[l + 192]);
    #pragma unroll
    for (int off = 32; off > 0; off >>= 1) v += __shfl_down(v, off);
    if (l == 0) out[0] = v;
}

extern "C" void kernel_launch(void* const* d_in, const int* in_sizes, int n_in,
                              void* d_out, int out_size, void* d_ws, size_t ws_size,
                              hipStream_t stream)
{
    const float* S   = (const float*)d_in[0];
    const void*  tgt = d_in[1];
    const void*  msk = d_in[2];
    float* out = (float*)d_out;
    float* ws  = (float*)d_ws;

    crf_chain_kernel<<<256, 512, 0, stream>>>(S, tgt, msk, ws);
    crf_reduce_kernel<<<1, 64, 0, stream>>>(ws, out);
}

// Round 4
// 131.456 us; speedup vs baseline: 2.2265x; 1.5965x over previous
//
#include <hip/hip_runtime.h>

// CRF forward loss, MI355X — exp-domain, 8-wave split, depth-4 prefetch,
// drain-free barrier (1 per step).
// Grid 256 = (batch 128) x (chain 2). Block 512 = 8 waves, lane = tag j.
// State u_i = 2^(st_i - Mg). Step: partial^w_j = sum_c E[i0+c][j]*u_{i0+c};
// u'_j = sum_w partial^w_j. E = 2^(sc*log2e) built off-chain from prefetch.
// scores(tau) lives in r[tau&3]; step t refills r[t&3] <- scores(t+4).

constexpr int SEQ = 256;
constexpr int NTAG = 48;
constexpr int START_TAG = 46;
constexpr int END_TAG = 47;
constexpr float L2E = 1.4426950408889634f; // log2(e)
constexpr float LN2 = 0.6931471805599453f;
constexpr int W = 8;   // waves
constexpr int C = 6;   // i-rows per wave

__device__ __forceinline__ float fexp2(float x) { return __builtin_amdgcn_exp2f(x); }
__device__ __forceinline__ float flog2(float x) { return __builtin_amdgcn_logf(x); }
__device__ __forceinline__ float rlane(float v, int lane) {
    return __uint_as_float(__builtin_amdgcn_readlane(__float_as_uint(v), lane));
}

__global__ __launch_bounds__(512, 1)
void crf_chain_kernel(const float* __restrict__ S,
                      const void* __restrict__ tgtv,
                      const void* __restrict__ mskv,
                      float* __restrict__ ws)
{
    const int bid  = blockIdx.x;
    const int b    = bid & 127;          // batch
    const int tagc = bid >> 7;           // 0: partition, 1: tag_partition
    const int tid  = threadIdx.x;
    const int k    = tid >> 6;           // wave id
    const int j    = tid & 63;           // lane = output tag column
    const bool jok = (j < NTAG);
    const int jj   = jok ? j : 0;
    const int i0   = k * C;

    // dtype detection: packed bool (1B) vs int32 (mask[0..3] all true)
    const bool pack8 = (((const int*)mskv)[0] != 1);
    const unsigned char* msk8  = (const unsigned char*)mskv;
    const int*           msk32 = (const int*)mskv;
    const unsigned char* tgt8  = (const unsigned char*)tgtv;
    const int*           tgt32 = (const int*)tgtv;

    auto ldtgt = [&](int t) -> int {
        int ti = (b * SEQ + t) * NTAG + jj;
        return pack8 ? (int)tgt8[ti] : tgt32[ti];
    };

    // sequence length via ballots (256 mask entries, 4 per lane)
    int len = 0;
    #pragma unroll
    for (int r = 0; r < 4; ++r) {
        int idx = b * SEQ + r * 64 + j;
        int mm = pack8 ? (msk8[idx] != 0) : (msk32[idx] != 0);
        len += (int)__popcll(__ballot(mm));
    }

    __shared__ float s_part[2][W][64];   // double-buffered partials

    const size_t sb   = (size_t)b * SEQ * NTAG * NTAG;
    const float  bias = jok ? 0.0f : -200.0f;   // pad columns -> E == 0
    const float* Sp   = S + sb + (size_t)i0 * NTAG + jj;  // + t*2304 + c*48

    // t=0 init: st0_j = sc[0,START,j]*log2e; u = 2^(st0 - M0) (all waves)
    float st0 = S[sb + START_TAG * NTAG + jj] * L2E;
    if (!jok) st0 = -1e30f;
    float M0 = st0;
    #pragma unroll
    for (int off = 1; off < 64; off <<= 1) M0 = fmaxf(M0, __shfl_xor(M0, off));
    float u = jok ? fexp2(st0 - M0) : 0.0f;
    if (tagc && jok) {
        int tv0i = ldtgt(0);
        if (tv0i) u = 0.0f;
    }
    float Mg = M0;

    // prologue: scores(1..4) -> r1,r2,r3,r0 ; E1 <- exp2(scores(1)); tv(1..4)
    float r0v[C], r1v[C], r2v[C], r3v[C], E0[C], E1[C];
    #pragma unroll
    for (int c = 0; c < C; ++c) r1v[c] = Sp[(size_t)1 * 2304 + c * NTAG];
    #pragma unroll
    for (int c = 0; c < C; ++c) r2v[c] = Sp[(size_t)2 * 2304 + c * NTAG];
    #pragma unroll
    for (int c = 0; c < C; ++c) r3v[c] = Sp[(size_t)3 * 2304 + c * NTAG];
    #pragma unroll
    for (int c = 0; c < C; ++c) r0v[c] = Sp[(size_t)4 * 2304 + c * NTAG];
    #pragma unroll
    for (int c = 0; c < C; ++c) E1[c] = fexp2(fmaf(r1v[c], L2E, bias));
    int tv1 = 0, tv2 = 0, tv3 = 0, tv0 = 0;
    if (tagc) { tv1 = ldtgt(1); tv2 = ldtgt(2); tv3 = ldtgt(3); tv0 = ldtgt(4); }

    // step t: refill rFill <- scores(t+4); consume Ecur; build Eoth <- rMid.
    auto body = [&](float (&rFill)[C], float (&rMid)[C],
                    float (&Ecur)[C], float (&Eoth)[C], int& tvSlot, int t) {
        const int tvUse = tvSlot;
        if (t + 4 < len) {
            const float* p = Sp + (size_t)(t + 4) * 2304;
            #pragma unroll
            for (int c = 0; c < C; ++c) rFill[c] = p[c * NTAG];
            if (tagc) tvSlot = ldtgt(t + 4);
        }
        __builtin_amdgcn_sched_barrier(0);   // pin prefetch issue here
        // this wave's partial: sum_c E[c] * u_{i0+c} (broadcast via readlane)
        float p0 = 0.f, p1 = 0.f;
        #pragma unroll
        for (int c = 0; c < C; c += 2) {
            p0 = fmaf(Ecur[c],     rlane(u, i0 + c),     p0);
            p1 = fmaf(Ecur[c + 1], rlane(u, i0 + c + 1), p1);
        }
        s_part[t & 1][k][j] = p0 + p1;
        // next step's E (state-independent) — overlaps barrier arrival
        if (t + 1 < len) {
            #pragma unroll
            for (int c = 0; c < C; ++c)
                Eoth[c] = fexp2(fmaf(rMid[c], L2E, bias));
        }
        __builtin_amdgcn_sched_barrier(0);
        asm volatile("s_waitcnt lgkmcnt(0)");   // LDS write visible; vmcnt untouched
        __builtin_amdgcn_sched_barrier(0);
        __builtin_amdgcn_s_barrier();
        __builtin_amdgcn_sched_barrier(0);
        float q0 = s_part[t & 1][0][j] + s_part[t & 1][1][j];
        float q1 = s_part[t & 1][2][j] + s_part[t & 1][3][j];
        float q2 = s_part[t & 1][4][j] + s_part[t & 1][5][j];
        float q3 = s_part[t & 1][6][j] + s_part[t & 1][7][j];
        float un = (q0 + q1) + (q2 + q3);
        if (tagc && tvUse) un = 0.0f;        // target mask: exact zero
        if (!jok) un = 0.0f;
        if ((t & 7) == 0) {                  // renorm: max(u) -> [0.5,1)
            float mx = un;
            #pragma unroll
            for (int off = 1; off < 64; off <<= 1) mx = fmaxf(mx, __shfl_xor(mx, off));
            int ex = (int)((__float_as_uint(mx) >> 23) & 0xFF) - 126;
            un = ldexpf(un, -ex);
            Mg += (float)ex;
        }
        u = un;
    };

    int t = 1;
    for (; t + 3 < len; t += 4) {            // static buffer slots, unroll 4
        body(r1v, r2v, E1, E0, tv1, t);
        body(r2v, r3v, E0, E1, tv2, t + 1);
        body(r3v, r0v, E1, E0, tv3, t + 2);
        body(r0v, r1v, E0, E1, tv0, t + 3);
    }
    for (; t < len; ++t) {                   // 0-3 tail steps, uniform switch
        switch (t & 3) {
        case 1: body(r1v, r2v, E1, E0, tv1, t); break;
        case 2: body(r2v, r3v, E0, E1, tv2, t); break;
        case 3: body(r3v, r0v, E1, E0, tv3, t); break;
        default: body(r0v, r1v, E0, E1, tv0, t); break;
        }
    }

    if (k == 0 && j == END_TAG) {
        float r = (Mg + flog2(u)) * LN2;     // back to ln domain
        if (tagc) r = (u == 0.0f) ? 0.0f : -r;
        ws[bid] = r;
    }
}

__global__ void crf_reduce_kernel(const float* __restrict__ ws, float* __restrict__ out)
{
    int l = threadIdx.x;                     // 64 threads
    float v = (ws[l] + ws[l + 64]) + (ws[l + 128] + ws[l + 192]);
    #pragma unroll
    for (int off = 32; off > 0; off >>= 1) v += __shfl_down(v, off);
    if (l == 0) out[0] = v;
}

extern "C" void kernel_launch(void* const* d_in, const int* in_sizes, int n_in,
                              void* d_out, int out_size, void* d_ws, size_t ws_size,
                              hipStream_t stream)
{
    const float* S   = (const float*)d_in[0];
    const void*  tgt = d_in[1];
    const void*  msk = d_in[2];
    float* out = (float*)d_out;
    float* ws  = (float*)d_ws;

    crf_chain_kernel<<<256, 512, 0, stream>>>(S, tgt, msk, ws);
    crf_reduce_kernel<<<1, 64, 0, stream>>>(ws, out);
}

// Round 5
// 130.165 us; speedup vs baseline: 2.2485x; 1.0099x over previous
//
#include <hip/hip_runtime.h>

// CRF forward loss, MI355X — exp-domain, 4-wave split, LDS 6-slot score ring
// staged via global_load_lds + counted vmcnt(9) (never drained in-loop).
// Grid 256 = (batch 128) x (chain 2). Block 256 = 4 waves, lane = tag j.
// State u_i = 2^(st_i - Mg). Step: partial^w_j = sum_c E[i0+c][j]*u_{i0+c};
// u'_j = sum_w partial^w_j. E = 2^(sc*log2e), built from LDS one step ahead.
// Wave k stages and reads ONLY its own 12 rows -> staging is wave-private.

constexpr int SEQ = 256;
constexpr int NTAG = 48;
constexpr int START_TAG = 46;
constexpr int END_TAG = 47;
constexpr float L2E = 1.4426950408889634f; // log2(e)
constexpr float LN2 = 0.6931471805599453f;
constexpr int W = 4;    // waves
constexpr int C = 12;   // i-rows per wave

constexpr int SLAB = NTAG * NTAG * 4;     // 9216 B per timestep
constexpr int NBUF = 6;                   // score ring slots
constexpr int BUFS = NBUF * SLAB;         // 55296
constexpr int PART_OFF = BUFS + 192;      // 192B pad for clamped-lane overrun
constexpr int TGT_OFF  = PART_OFF + 2048; // partials: 2 x 4 x 64 floats
constexpr int LDS_TOT  = TGT_OFF + 12352; // tgt bytes 12288 + 64 pad = 69888 B

__device__ __forceinline__ float fexp2(float x) { return __builtin_amdgcn_exp2f(x); }
__device__ __forceinline__ float flog2(float x) { return __builtin_amdgcn_logf(x); }
__device__ __forceinline__ float rlane(float v, int l) {
    return __uint_as_float(__builtin_amdgcn_readlane(__float_as_uint(v), l));
}

__global__ __launch_bounds__(256, 1)
void crf_chain_kernel(const float* __restrict__ S,
                      const void* __restrict__ tgtv,
                      const void* __restrict__ mskv,
                      float* __restrict__ ws)
{
    __shared__ __align__(16) unsigned char lds[LDS_TOT];
    const int bid  = blockIdx.x;
    const int b    = bid & 127;          // batch
    const int tagc = bid >> 7;           // 0: partition, 1: tag_partition
    const int tid  = threadIdx.x;
    const int k    = tid >> 6;           // wave id
    const int j    = tid & 63;           // lane = output tag column
    const bool jok = (j < NTAG);
    const int jj   = jok ? j : 0;
    const int i0   = k * C;

    // dtype detection: packed bool (1B) vs int32 (mask[0..3] all true)
    const bool pack8 = (((const int*)mskv)[0] != 1);
    const unsigned char* msk8  = (const unsigned char*)mskv;
    const int*           msk32 = (const int*)mskv;

    // sequence length via ballots (256 mask entries, 4 per lane)
    int len = 0;
    #pragma unroll
    for (int r = 0; r < 4; ++r) {
        int idx = b * SEQ + r * 64 + j;
        int mm = pack8 ? (msk8[idx] != 0) : (msk32[idx] != 0);
        len += (int)__popcll(__ballot(mm));
    }

    // ---- prologue LDS init: target row (tagc only) + pads ----
    if (tagc) {
        if (pack8) {
            const int4* src = (const int4*)((const unsigned char*)tgtv + (size_t)b * 12288);
            int4* dst = (int4*)(lds + TGT_OFF);
            #pragma unroll
            for (int r = 0; r < 3; ++r) dst[tid * 3 + r] = src[tid * 3 + r];
        } else {
            const int4* src = (const int4*)((const int*)tgtv + (size_t)b * 12288);
            unsigned* dst = (unsigned*)(lds + TGT_OFF);
            #pragma unroll
            for (int r = 0; r < 12; ++r) {
                int4 v = src[tid * 12 + r];
                dst[tid * 12 + r] = (unsigned)((v.x & 1) | ((v.y & 1) << 8) |
                                               ((v.z & 1) << 16) | ((v.w & 1) << 24));
            }
        }
    }
    if (tid < 12) *(float4*)(lds + BUFS + tid * 16) = make_float4(0.f, 0.f, 0.f, 0.f);
    if (tid < 4)  *(float4*)(lds + TGT_OFF + 12288 + tid * 16) = make_float4(0.f, 0.f, 0.f, 0.f);
    __syncthreads();

    const size_t sbf = (size_t)b * SEQ * NTAG * NTAG;      // float index of batch slab
    const float  bias = jok ? 0.0f : -200.0f;              // pad cols -> E == 0

    // t=0 init: st0_j = sc[0,START,j]*log2e; u = 2^(st0 - M0)
    float st0 = S[sbf + START_TAG * NTAG + jj] * L2E;
    if (!jok) st0 = -1e30f;
    float M0 = st0;
    #pragma unroll
    for (int off = 1; off < 64; off <<= 1) M0 = fmaxf(M0, __shfl_xor(M0, off));
    float u = jok ? fexp2(st0 - M0) : 0.0f;
    if (tagc && jok) {
        int tv0 = lds[TGT_OFF + j];        // t=0 target (already staged)
        if (tv0) u = 0.0f;
    }
    float Mg = M0;

    // ---- staging machinery: wave k covers bytes [2304k, 2304k+2304) of a slab
    const unsigned char* Sb = (const unsigned char*)S + sbf * 4;
    const int lo16 = k * 2304 + j * 16;
    const int lo4  = k * 2304 + 2048 + j * 4;

    auto stage = [&](int tau, int slot) {
        const unsigned char* g = Sb + (size_t)tau * SLAB;
        unsigned char* l = lds + slot * SLAB + k * 2304;
        __builtin_amdgcn_global_load_lds(
            (const __attribute__((address_space(1))) void*)(g + lo16),
            (__attribute__((address_space(3))) void*)l, 16, 0, 0);
        __builtin_amdgcn_global_load_lds(
            (const __attribute__((address_space(1))) void*)(g + lo16 + 1024),
            (__attribute__((address_space(3))) void*)(l + 1024), 16, 0, 0);
        __builtin_amdgcn_global_load_lds(
            (const __attribute__((address_space(1))) void*)(g + lo4),
            (__attribute__((address_space(3))) void*)(l + 2048), 4, 0, 0);
    };

    // prologue: stage scores(1..5) into slots 1..5 (len >= 128)
    #pragma unroll
    for (int tau = 1; tau <= 5; ++tau) stage(tau, tau);
    asm volatile("s_waitcnt vmcnt(9)" ::: "memory");   // forces stages 1,2 done
    __builtin_amdgcn_sched_barrier(0);

    float EA[C], EB[C];
    {
        const float* ep = (const float*)(lds + 1 * SLAB + i0 * 192);
        #pragma unroll
        for (int c = 0; c < C; ++c) EA[c] = fexp2(fmaf(ep[c * 48 + j], L2E, bias));
    }

    float* part = (float*)(lds + PART_OFF);
    const unsigned char* tl = lds + TGT_OFF;
    int st_slot = 0;   // slot for tau = t+5 (t=1 -> 6%6 = 0)
    int rd_slot = 2;   // slot for t+1  (t=1 -> 2)

    auto body = [&](float (&Ecur)[C], float (&Enext)[C], int t, int pb) {
        int tvv = 0;
        if (tagc) tvv = tl[t * 48 + j];
        // this wave's partial: sum_c E[c] * u_{i0+c}
        float p0 = 0.f, p1 = 0.f;
        #pragma unroll
        for (int c = 0; c < C; c += 2) {
            p0 = fmaf(Ecur[c],     rlane(u, i0 + c),     p0);
            p1 = fmaf(Ecur[c + 1], rlane(u, i0 + c + 1), p1);
        }
        part[pb * 256 + k * 64 + j] = p0 + p1;
        // stage scores(t+5); always issue (clamped) so vmcnt count stays uniform
        int tau = (t + 5 < len) ? (t + 5) : (len - 1);
        stage(tau, st_slot);
        if (++st_slot >= NBUF) st_slot = 0;
        // build E(t+1) from slot (t+1)%6 (completion forced at step t-1's wait)
        if (t + 1 < len) {
            const float* ep = (const float*)(lds + rd_slot * SLAB + i0 * 192);
            #pragma unroll
            for (int c = 0; c < C; ++c)
                Enext[c] = fexp2(fmaf(ep[c * 48 + j], L2E, bias));
        }
        if (++rd_slot >= NBUF) rd_slot = 0;
        // drain-free sync: LDS ordered, global stages stay in flight (vmcnt 9)
        __builtin_amdgcn_sched_barrier(0);
        asm volatile("s_waitcnt lgkmcnt(0)" ::: "memory");
        asm volatile("s_waitcnt vmcnt(9)" ::: "memory");
        __builtin_amdgcn_sched_barrier(0);
        __builtin_amdgcn_s_barrier();
        __builtin_amdgcn_sched_barrier(0);
        // combine 4 partials
        float q0 = part[pb * 256 + j]       + part[pb * 256 + 64 + j];
        float q1 = part[pb * 256 + 128 + j] + part[pb * 256 + 192 + j];
        float un = q0 + q1;
        if (tagc && tvv) un = 0.0f;          // target mask: exact zero
        if (!jok) un = 0.0f;
        if ((t & 7) == 0) {                  // renorm: max(u) -> [0.5,1)
            float mx = un;
            #pragma unroll
            for (int off = 1; off < 64; off <<= 1) mx = fmaxf(mx, __shfl_xor(mx, off));
            int ex = (int)((__float_as_uint(mx) >> 23) & 0xFF) - 126;
            un = ldexpf(un, -ex);
            Mg += (float)ex;
        }
        u = un;
    };

    int t = 1;
    for (; t + 1 < len; t += 2) {           // static E rotation, unroll 2
        body(EA, EB, t, 1);
        body(EB, EA, t + 1, 0);
    }
    if (t < len) body(EA, EB, t, 1);

    if (k == 0 && j == END_TAG) {
        float r = (Mg + flog2(u)) * LN2;     // back to ln domain
        if (tagc) r = (u == 0.0f) ? 0.0f : -r;
        ws[bid] = r;
    }
}

__global__ void crf_reduce_kernel(const float* __restrict__ ws, float* __restrict__ out)
{
    int l = threadIdx.x;                     // 64 threads
    float v = (ws[l] + ws[l + 64]) + (ws[l + 128] + ws[l + 192]);
    #pragma unroll
    for (int off = 32; off > 0; off >>= 1) v += __shfl_down(v, off);
    if (l == 0) out[0] = v;
}

extern "C" void kernel_launch(void* const* d_in, const int* in_sizes, int n_in,
                              void* d_out, int out_size, void* d_ws, size_t ws_size,
                              hipStream_t stream)
{
    const float* S   = (const float*)d_in[0];
    const void*  tgt = d_in[1];
    const void*  msk = d_in[2];
    float* out = (float*)d_out;
    float* ws  = (float*)d_ws;

    crf_chain_kernel<<<256, 256, 0, stream>>>(S, tgt, msk, ws);
    crf_reduce_kernel<<<1, 64, 0, stream>>>(ws, out);
}